// Round 1
// baseline (102.008 us; speedup 1.0000x reference)
//
#include <hip/hip_runtime.h>

// Problem constants (fixed by reference setup_inputs)
#define Bn 32
#define Cn 512
#define HWn 4096   // 64*64
#define Kn 256     // C/2

// ---------------------------------------------------------------------------
// Kernel 1: per-(b,c) mean over H*W. One block per (b,c) slice (16 KB
// contiguous). 256 threads x 4 float4 each = 4096 floats. Double accumulator
// to match the near-exact numpy pairwise mean (top-k order depends on it).
// ---------------------------------------------------------------------------
__global__ __launch_bounds__(256) void eca_mean_kernel(
    const float* __restrict__ x, float* __restrict__ y) {
    int bc = blockIdx.x;  // 0 .. Bn*Cn-1
    const float4* p = (const float4*)(x + (size_t)bc * HWn);
    int t = threadIdx.x;
    double s = 0.0;
#pragma unroll
    for (int i = 0; i < 4; ++i) {
        float4 v = p[t + i * 256];
        s += (double)v.x + (double)v.y + (double)v.z + (double)v.w;
    }
    __shared__ double sm[256];
    sm[t] = s;
    __syncthreads();
    for (int off = 128; off > 0; off >>= 1) {
        if (t < off) sm[t] += sm[t + off];
        __syncthreads();
    }
    if (t == 0) y[bc] = (float)(sm[0] * (1.0 / 4096.0));
}

// ---------------------------------------------------------------------------
// Kernel 2: conv1d(pad=1) + sigmoid + top-k rank per batch. One block per
// batch, 512 threads (one per channel). Rank-by-counting reproduces
// lax.top_k's descending order with stable (lower-index-first) ties.
// Conv replicated as numpy does it: separate fp32 mul/adds, left-to-right,
// no FMA contraction (__fmul_rn/__fadd_rn).
// ---------------------------------------------------------------------------
__global__ __launch_bounds__(Cn) void eca_topk_kernel(
    const float* __restrict__ y, const float* __restrict__ w,
    int* __restrict__ idx) {
    int b = blockIdx.x;
    int c = threadIdx.x;  // 0 .. Cn-1
    __shared__ float sc[Cn];

    float w0 = w[0], w1 = w[1], w2 = w[2];
    float ym1 = (c == 0) ? 0.0f : y[b * Cn + c - 1];
    float y0 = y[b * Cn + c];
    float yp1 = (c == Cn - 1) ? 0.0f : y[b * Cn + c + 1];

    float s = __fmul_rn(w0, ym1);
    s = __fadd_rn(s, __fmul_rn(w1, y0));
    s = __fadd_rn(s, __fmul_rn(w2, yp1));
    float sig = 1.0f / (1.0f + expf(-s));

    sc[c] = sig;
    __syncthreads();

    int rank = 0;
    for (int j = 0; j < Cn; ++j) {
        float o = sc[j];  // same address across lanes -> LDS broadcast
        rank += (o > sig || (o == sig && j < c)) ? 1 : 0;
    }
    if (rank < Kn) idx[b * Kn + rank] = c;
}

// ---------------------------------------------------------------------------
// Kernel 3: gather selected channel slices. One block per (b, rank) output
// slice; scalar index load (uniform across block), then coalesced float4
// copy of 16 KB.
// ---------------------------------------------------------------------------
__global__ __launch_bounds__(256) void eca_gather_kernel(
    const float* __restrict__ x, const int* __restrict__ idx,
    float* __restrict__ out) {
    int bj = blockIdx.x;  // b*Kn + j
    int b = bj >> 8;      // Kn == 256
    int c = idx[bj];
    const float4* src = (const float4*)(x + ((size_t)b * Cn + c) * HWn);
    float4* dst = (float4*)(out + (size_t)bj * HWn);
    int t = threadIdx.x;
#pragma unroll
    for (int i = 0; i < 4; ++i) dst[t + i * 256] = src[t + i * 256];
}

extern "C" void kernel_launch(void* const* d_in, const int* in_sizes, int n_in,
                              void* d_out, int out_size, void* d_ws,
                              size_t ws_size, hipStream_t stream) {
    const float* x = (const float*)d_in[0];
    const float* w = (const float*)d_in[1];
    float* out = (float*)d_out;

    float* y = (float*)d_ws;                                  // Bn*Cn floats
    int* idx = (int*)((char*)d_ws + Bn * Cn * sizeof(float)); // Bn*Kn ints

    eca_mean_kernel<<<Bn * Cn, 256, 0, stream>>>(x, y);
    eca_topk_kernel<<<Bn, Cn, 0, stream>>>(y, w, idx);
    eca_gather_kernel<<<Bn * Kn, 256, 0, stream>>>(x, idx, out);
}

// Round 3
// 99.312 us; speedup vs baseline: 1.0271x; 1.0271x over previous
//
#include <hip/hip_runtime.h>

// Problem constants (fixed by reference setup_inputs)
#define Bn 32
#define Cn 512
#define HWn 4096   // 64*64
#define Kn 256     // C/2

typedef float vfloat4 __attribute__((ext_vector_type(4)));

// ---------------------------------------------------------------------------
// Kernel 1: per-(b,c) mean over H*W. One block per (b,c) slice (16 KB
// contiguous). 256 threads x 4 float4 each = 4096 floats. Double accumulator
// to match the near-exact numpy pairwise mean (top-k order depends on it).
// Regular (temporal) loads on purpose: we WANT x resident in L3 so the
// gather pass can hit it.
// ---------------------------------------------------------------------------
__global__ __launch_bounds__(256) void eca_mean_kernel(
    const float* __restrict__ x, float* __restrict__ y) {
    int bc = blockIdx.x;  // 0 .. Bn*Cn-1
    const vfloat4* p = (const vfloat4*)(x + (size_t)bc * HWn);
    int t = threadIdx.x;
    double s = 0.0;
#pragma unroll
    for (int i = 0; i < 4; ++i) {
        vfloat4 v = p[t + i * 256];
        s += (double)v.x + (double)v.y + (double)v.z + (double)v.w;
    }
    __shared__ double sm[256];
    sm[t] = s;
    __syncthreads();
    for (int off = 128; off > 0; off >>= 1) {
        if (t < off) sm[t] += sm[t + off];
        __syncthreads();
    }
    if (t == 0) y[bc] = (float)(sm[0] * (1.0 / 4096.0));
}

// ---------------------------------------------------------------------------
// Kernel 2: conv1d(pad=1) + sigmoid + top-k rank per batch. One block per
// batch, 512 threads (one per channel). Rank-by-counting reproduces
// lax.top_k's descending order with stable (lower-index-first) ties.
// Conv replicated as numpy does it: separate fp32 mul/adds, left-to-right,
// no FMA contraction (__fmul_rn/__fadd_rn).
// ---------------------------------------------------------------------------
__global__ __launch_bounds__(Cn) void eca_topk_kernel(
    const float* __restrict__ y, const float* __restrict__ w,
    int* __restrict__ idx) {
    int b = blockIdx.x;
    int c = threadIdx.x;  // 0 .. Cn-1
    __shared__ float sc[Cn];

    float w0 = w[0], w1 = w[1], w2 = w[2];
    float ym1 = (c == 0) ? 0.0f : y[b * Cn + c - 1];
    float y0 = y[b * Cn + c];
    float yp1 = (c == Cn - 1) ? 0.0f : y[b * Cn + c + 1];

    float s = __fmul_rn(w0, ym1);
    s = __fadd_rn(s, __fmul_rn(w1, y0));
    s = __fadd_rn(s, __fmul_rn(w2, yp1));
    float sig = 1.0f / (1.0f + expf(-s));

    sc[c] = sig;
    __syncthreads();

    int rank = 0;
    for (int j = 0; j < Cn; ++j) {
        float o = sc[j];  // same address across lanes -> LDS broadcast
        rank += (o > sig || (o == sig && j < c)) ? 1 : 0;
    }
    if (rank < Kn) idx[b * Kn + rank] = c;
}

// ---------------------------------------------------------------------------
// Kernel 3: gather selected channel slices. One block per (b, rank) output
// slice; scalar index load (uniform across block), then coalesced float4
// copy of 16 KB. Reads are temporal (hope for L3 hits on the just-streamed
// x); stores are NON-TEMPORAL so the 128 MiB of output doesn't evict x
// from the Infinity Cache mid-gather.
// ---------------------------------------------------------------------------
__global__ __launch_bounds__(256) void eca_gather_kernel(
    const float* __restrict__ x, const int* __restrict__ idx,
    float* __restrict__ out) {
    int bj = blockIdx.x;  // b*Kn + j
    int b = bj >> 8;      // Kn == 256
    int c = idx[bj];
    const vfloat4* src = (const vfloat4*)(x + ((size_t)b * Cn + c) * HWn);
    vfloat4* dst = (vfloat4*)(out + (size_t)bj * HWn);
    int t = threadIdx.x;

    vfloat4 v[4];
#pragma unroll
    for (int i = 0; i < 4; ++i) v[i] = src[t + i * 256];
#pragma unroll
    for (int i = 0; i < 4; ++i)
        __builtin_nontemporal_store(v[i], &dst[t + i * 256]);
}

extern "C" void kernel_launch(void* const* d_in, const int* in_sizes, int n_in,
                              void* d_out, int out_size, void* d_ws,
                              size_t ws_size, hipStream_t stream) {
    const float* x = (const float*)d_in[0];
    const float* w = (const float*)d_in[1];
    float* out = (float*)d_out;

    float* y = (float*)d_ws;                                  // Bn*Cn floats
    int* idx = (int*)((char*)d_ws + Bn * Cn * sizeof(float)); // Bn*Kn ints

    eca_mean_kernel<<<Bn * Cn, 256, 0, stream>>>(x, y);
    eca_topk_kernel<<<Bn, Cn, 0, stream>>>(y, w, idx);
    eca_gather_kernel<<<Bn * Kn, 256, 0, stream>>>(x, idx, out);
}

// Round 4
// 98.116 us; speedup vs baseline: 1.0397x; 1.0122x over previous
//
#include <hip/hip_runtime.h>

// Problem constants (fixed by reference setup_inputs)
#define Bn 32
#define Cn 512
#define HWn 4096   // 64*64
#define Kn 256     // C/2

typedef float vfloat4 __attribute__((ext_vector_type(4)));

// ---------------------------------------------------------------------------
// Kernel 1: per-(b,c) mean over H*W. ONE WAVE per 16 KiB channel slice:
// 64 lanes x 16 dwordx4 loads, double accumulate, 6-step shfl_xor butterfly.
// No LDS, no barriers (vs round-3's 8-syncthreads LDS tree). Double keeps
// the fp32-rounded result order-independent (top-k rank depends on it).
// ---------------------------------------------------------------------------
__global__ __launch_bounds__(256) void eca_mean_kernel(
    const float* __restrict__ x, float* __restrict__ y) {
    int slice = (blockIdx.x << 2) + (threadIdx.x >> 6);  // grid 4096, 4 waves
    int lane = threadIdx.x & 63;
    const vfloat4* p = (const vfloat4*)(x + (size_t)slice * HWn);
    double s = 0.0;
#pragma unroll
    for (int i = 0; i < 16; ++i) {
        vfloat4 v = p[lane + (i << 6)];
        s += ((double)v.x + (double)v.y) + ((double)v.z + (double)v.w);
    }
#pragma unroll
    for (int m = 32; m; m >>= 1) s += __shfl_xor(s, m, 64);
    if (lane == 0) y[slice] = (float)(s * (1.0 / 4096.0));
}

// ---------------------------------------------------------------------------
// Kernel 2: conv1d(pad=1) + sigmoid + top-k rank per batch. One block per
// batch, 512 threads (one per channel). Rank-by-counting reproduces
// lax.top_k's descending order with stable (lower-index-first) ties.
// Conv replicated as numpy does it: separate fp32 mul/adds, left-to-right,
// no FMA contraction (__fmul_rn/__fadd_rn).
// ---------------------------------------------------------------------------
__global__ __launch_bounds__(Cn) void eca_topk_kernel(
    const float* __restrict__ y, const float* __restrict__ w,
    int* __restrict__ idx) {
    int b = blockIdx.x;
    int c = threadIdx.x;  // 0 .. Cn-1
    __shared__ float sc[Cn];

    float w0 = w[0], w1 = w[1], w2 = w[2];
    float ym1 = (c == 0) ? 0.0f : y[b * Cn + c - 1];
    float y0 = y[b * Cn + c];
    float yp1 = (c == Cn - 1) ? 0.0f : y[b * Cn + c + 1];

    float s = __fmul_rn(w0, ym1);
    s = __fadd_rn(s, __fmul_rn(w1, y0));
    s = __fadd_rn(s, __fmul_rn(w2, yp1));
    float sig = 1.0f / (1.0f + expf(-s));

    sc[c] = sig;
    __syncthreads();

    int rank = 0;
    for (int j = 0; j < Cn; ++j) {
        float o = sc[j];  // same address across lanes -> LDS broadcast
        rank += (o > sig || (o == sig && j < c)) ? 1 : 0;
    }
    if (rank < Kn) idx[b * Kn + rank] = c;
}

// ---------------------------------------------------------------------------
// Kernel 3: gather selected channel slices. One block per (b, rank) output
// slice; scalar index load (uniform across block), then coalesced float4
// copy of 16 KB. Stores are non-temporal (write-only output, never re-read).
// ---------------------------------------------------------------------------
__global__ __launch_bounds__(256) void eca_gather_kernel(
    const float* __restrict__ x, const int* __restrict__ idx,
    float* __restrict__ out) {
    int bj = blockIdx.x;  // b*Kn + j
    int b = bj >> 8;      // Kn == 256
    int c = idx[bj];
    const vfloat4* src = (const vfloat4*)(x + ((size_t)b * Cn + c) * HWn);
    vfloat4* dst = (vfloat4*)(out + (size_t)bj * HWn);
    int t = threadIdx.x;

    vfloat4 v[4];
#pragma unroll
    for (int i = 0; i < 4; ++i) v[i] = src[t + i * 256];
#pragma unroll
    for (int i = 0; i < 4; ++i)
        __builtin_nontemporal_store(v[i], &dst[t + i * 256]);
}

extern "C" void kernel_launch(void* const* d_in, const int* in_sizes, int n_in,
                              void* d_out, int out_size, void* d_ws,
                              size_t ws_size, hipStream_t stream) {
    const float* x = (const float*)d_in[0];
    const float* w = (const float*)d_in[1];
    float* out = (float*)d_out;

    float* y = (float*)d_ws;                                  // Bn*Cn floats
    int* idx = (int*)((char*)d_ws + Bn * Cn * sizeof(float)); // Bn*Kn ints

    eca_mean_kernel<<<(Bn * Cn) / 4, 256, 0, stream>>>(x, y);
    eca_topk_kernel<<<Bn, Cn, 0, stream>>>(y, w, idx);
    eca_gather_kernel<<<Bn * Kn, 256, 0, stream>>>(x, idx, out);
}